// Round 4
// baseline (155.875 us; speedup 1.0000x reference)
//
#include <hip/hip_runtime.h>
#include <cstdint>
#include <cstddef>
#include <math.h>

#define S_LEN  256
#define BATCH  32
#define HID    256
#define EMB    256
#define TSTEPS 10

// ---------------------------------------------------------------------------
// ONE kernel, one dispatch, no workspace. 32 blocks (one per batch element)
// x 512 threads. Per-block silence proof (Cauchy-Schwarz over THIS block's
// tokens): max X1 <= max(b1) + maxE*maxW < thr1*(1-leak1) => layer 1 never
// spikes => layer-2 input is exactly b2 => (checked) layer 2 never spikes =>
// acc accumulates exactly b3 per step. If additionally b3 == 0 and Wa1 is
// finite, h == 0 exactly and h@Wa1^T == 0 exactly => out = relu(ba1)@Wa2^T
// + ba2 directly. If the proof fails, wave 0 runs the exact bit-level
// simulation (ballot spike masks, active-column sums).
//
// Memory-parallelism structure (the round-1 fusion's mistake, fixed): every
// scan phase uses 8 threads/row x 8 rows per wave-iteration, each thread
// reading 128 B contiguous (8 independent float4 loads) -> 64 independent
// 16 B loads in flight per wave -> latency-hidden gather at ~5 TB/s issue
// capability across 32 CUs, instead of one-row-at-a-time shfl-serialized.
// ---------------------------------------------------------------------------

__device__ __forceinline__ float wave_sum(float s) {
#pragma unroll
    for (int off = 1; off < 64; off <<= 1) s += __shfl_xor(s, off, 64);
    return s;
}

__global__ __launch_bounds__(512) void snn_one_kernel(
    const int* __restrict__ text, const float* __restrict__ emb,
    const float* __restrict__ W1, const float* __restrict__ b1,
    const float* __restrict__ W2, const float* __restrict__ b2,
    const float* __restrict__ W3, const float* __restrict__ b3,
    const float* __restrict__ thr1p, const float* __restrict__ leak1p,
    const float* __restrict__ thr2p, const float* __restrict__ leak2p,
    const float* __restrict__ Wa1, const float* __restrict__ ba1,
    const float* __restrict__ Wa2, const float* __restrict__ ba2,
    float* __restrict__ out)
{
    const int b    = blockIdx.x;   // batch element
    const int tid  = threadIdx.x;
    const int l    = tid & 63;     // lane
    const int w    = tid >> 6;     // wave 0..7
    const int p    = tid & 7;      // 128 B segment within a 1 KB row
    const int rsub = l >> 3;       // row-within-group 0..7

    __shared__ int   stok[S_LEN];
    __shared__ __align__(16) float hsh[HID];
    __shared__ float rsh[HID];
    __shared__ float redE[8], redW[4], redB[4];
    __shared__ int   redF[4], redNF[4];
    __shared__ int   sdec;

    // ---- stage this block's tokens (waves 0..3; loads overlap the scans) ----
    if (tid < S_LEN) stok[tid] = text[tid * BATCH + b];

    // ---- concurrent scans: waves 0..3 -> W1 norms, waves 4..7 -> Wa1 finite ----
    if (w < 4) {
        float mW = 0.f;
#pragma unroll
        for (int i = 0; i < 8; ++i) {
            const int row = w * 64 + i * 8 + rsub;
            const float4* __restrict__ r =
                (const float4*)(W1 + (size_t)row * EMB) + p * 8;
            float s = 0.f;
#pragma unroll
            for (int j = 0; j < 8; ++j) {
                const float4 v = r[j];
                s += v.x * v.x + v.y * v.y + v.z * v.z + v.w * v.w;
            }
#pragma unroll
            for (int off = 1; off < 8; off <<= 1) s += __shfl_xor(s, off, 64);
            mW = fmaxf(mW, isnan(s) ? INFINITY : s);
        }
#pragma unroll
        for (int off = 8; off < 64; off <<= 1) mW = fmaxf(mW, __shfl_xor(mW, off, 64));
        if (l == 0) redW[w] = mW;

        // ---- bias checks (exactly threads 0..255 = waves 0..3) ----
        const float thr2 = thr2p[0], leak2 = leak2p[0];
        const float c2   = thr2 * (1.0f - leak2) - 1e-4f * thr2 - 1e-6f;
        const float b1i  = b1[tid];
        const float b2i  = b2[tid];
        const float b3i  = b3[tid];
        float mB = isnan(b1i) ? INFINITY : b1i;
#pragma unroll
        for (int off = 1; off < 64; off <<= 1) mB = fmaxf(mB, __shfl_xor(mB, off, 64));
        const bool bad  = !(b2i < c2);                        // catches NaN too
        const bool b3nz = (b3i != 0.0f) || isnan(b3i);
        const unsigned long long mbad = __ballot(bad);
        const unsigned long long mnz  = __ballot(b3nz);
        if (l == 0) {
            redB[w] = mB;
            redF[w] = (mbad ? 1 : 0) | (mnz ? 2 : 0);
        }
    } else {
        const int w4 = w - 4;
        int nf = 0;
#pragma unroll
        for (int i = 0; i < 8; ++i) {
            const int row = w4 * 64 + i * 8 + rsub;
            const float4* __restrict__ r =
                (const float4*)(Wa1 + (size_t)row * HID) + p * 8;
#pragma unroll
            for (int j = 0; j < 8; ++j) {
                const float4 v = r[j];
                nf |= !isfinite(v.x) || !isfinite(v.y) ||
                      !isfinite(v.z) || !isfinite(v.w);
            }
        }
        const unsigned long long m = __ballot(nf != 0);
        if (l == 0) redNF[w4] = (m != 0ULL) ? 1 : 0;
    }
    __syncthreads();   // stok ready, scan partials in LDS

    // ---- emb-row norms over THIS block's 256 tokens (all 8 waves) ----
    float mE = 0.f;
#pragma unroll
    for (int i = 0; i < 4; ++i) {
        const int tok = stok[w * 32 + i * 8 + rsub];
        const float4* __restrict__ r =
            (const float4*)(emb + (size_t)tok * EMB) + p * 8;
        float s = 0.f;
#pragma unroll
        for (int j = 0; j < 8; ++j) {
            const float4 v = r[j];
            s += v.x * v.x + v.y * v.y + v.z * v.z + v.w * v.w;
        }
#pragma unroll
        for (int off = 1; off < 8; off <<= 1) s += __shfl_xor(s, off, 64);
        s = isnan(s) ? INFINITY : s;
        if (tok == 0) s = 0.f;        // padding row zeroed in the reference
        mE = fmaxf(mE, s);
    }
#pragma unroll
    for (int off = 8; off < 64; off <<= 1) mE = fmaxf(mE, __shfl_xor(mE, off, 64));
    if (l == 0) redE[w] = mE;
    __syncthreads();

    // ---- combine + decide (thread 0) ----
    if (tid == 0) {
        const float maxW2 = fmaxf(fmaxf(redW[0], redW[1]), fmaxf(redW[2], redW[3]));
        const float maxB1 = fmaxf(fmaxf(redB[0], redB[1]), fmaxf(redB[2], redB[3]));
        const int   flags = redF[0] | redF[1] | redF[2] | redF[3];
        const int   wnf   = redNF[0] | redNF[1] | redNF[2] | redNF[3];
        float maxE2 = 0.f;
#pragma unroll
        for (int i = 0; i < 8; ++i) maxE2 = fmaxf(maxE2, redE[i]);
        const float thr1 = thr1p[0], leak1 = leak1p[0];
        const float thr2 = thr2p[0], leak2 = leak2p[0];
        const bool bad = ((flags & 1) != 0) ||
                         !(leak1 >= 0.0f && leak1 < 1.0f &&
                           leak2 >= 0.0f && leak2 < 1.0f &&
                           thr1 > 0.0f && thr2 > 0.0f);
        const float bound  = sqrtf(maxE2 * maxW2) * 1.0001f + maxB1 + 1e-6f;
        const float c1     = thr1 * (1.0f - leak1) - 1e-4f * thr1 - 1e-6f;
        const bool  silent = !bad && (bound < c1);
        sdec = (silent ? 1 : 0) | (flags & 2) | (wnf ? 4 : 0);
    }
    __syncthreads();
    const int  dec    = sdec;
    const bool silent = (dec & 1) != 0;
    const bool b3anz  = (dec & 2) != 0;
    const bool wa1nf  = (dec & 4) != 0;

    if (silent && !b3anz && !wa1nf) {
        // ---- fast path: h == 0 exactly, Wa1 finite => h@Wa1^T == 0 ----
        if (w == 0) {
            float q = 0.f;
#pragma unroll
            for (int k = 0; k < 4; ++k) {
                const int i = l + 64 * k;
                q += Wa2[i] * fmaxf(ba1[i], 0.0f);
            }
            q = wave_sum(q);
            if (l == 0) out[b] = q + ba2[0];
        }
        return;                       // block-uniform, no sync below needed
    }

    if (silent) {
        // layers silent but b3 != 0: acc = b3 added S*T times in the
        // reference's sequential rounding order.
        if (tid < HID) {
            const float b3t = b3[tid];
            float a = 0.f;
            for (int st = 0; st < S_LEN * TSTEPS; ++st) a += b3t;
            hsh[tid] = a * (1.0f / (float)BATCH);
        }
    } else if (w == 0) {
        // -------- exact in-kernel fallback (wave 0, lane l = neurons l+64k) --
        const float thr1  = thr1p[0],  thr2  = thr2p[0];
        const float leak1 = leak1p[0], leak2 = leak2p[0];
        float b1f[4], b2f[4], b3f[4];
#pragma unroll
        for (int k = 0; k < 4; ++k) {
            b1f[k] = b1[l + 64 * k];
            b2f[k] = b2[l + 64 * k];
            b3f[k] = b3[l + 64 * k];
        }
        float m1[4]  = {0.f, 0.f, 0.f, 0.f};
        float m2[4]  = {0.f, 0.f, 0.f, 0.f};
        float acc[4] = {0.f, 0.f, 0.f, 0.f};

        for (int s = 0; s < S_LEN; ++s) {
            float X1c[4];
            {
                int tok = stok[s];
                tok = __builtin_amdgcn_readfirstlane(tok);
                const float4* __restrict__ xr = (const float4*)(emb + (size_t)tok * EMB);
                const float sc = (tok == 0) ? 0.0f : 1.0f;
#pragma unroll
                for (int k = 0; k < 4; ++k) {
                    const float4* __restrict__ wr =
                        (const float4*)(W1 + (size_t)(l + 64 * k) * EMB);
                    float a = 0.f;
                    for (int j4 = 0; j4 < EMB / 4; ++j4) {
                        float4 wv = wr[j4];
                        float4 xv = xr[j4];
                        a += wv.x * xv.x + wv.y * xv.y + wv.z * xv.z + wv.w * xv.w;
                    }
                    X1c[k] = b1f[k] + sc * a;
                }
            }

#pragma unroll
            for (int t = 0; t < TSTEPS; ++t) {
                unsigned long long msk[4];

#pragma unroll
                for (int k = 0; k < 4; ++k) {
                    m1[k] = fmaf(m1[k], leak1, X1c[k]);
                    const bool sp = m1[k] > thr1;
                    msk[k] = __ballot(sp);
                    m1[k] -= sp ? thr1 : 0.f;
                }

                float d2[4] = {b2f[0], b2f[1], b2f[2], b2f[3]};
                if (msk[0] | msk[1] | msk[2] | msk[3]) {
#pragma unroll
                    for (int k2 = 0; k2 < 4; ++k2) {
                        unsigned long long m = msk[k2];
                        while (m) {
                            const int j = (k2 << 6) + __builtin_ctzll(m);
                            m &= m - 1;
#pragma unroll
                            for (int k = 0; k < 4; ++k)
                                d2[k] += W2[(size_t)(l + 64 * k) * HID + j];
                        }
                    }
                }

#pragma unroll
                for (int k = 0; k < 4; ++k) {
                    m2[k] = fmaf(m2[k], leak2, d2[k]);
                    const bool sp = m2[k] > thr2;
                    msk[k] = __ballot(sp);
                    m2[k] -= sp ? thr2 : 0.f;
                }

                float d3[4] = {b3f[0], b3f[1], b3f[2], b3f[3]};
                if (msk[0] | msk[1] | msk[2] | msk[3]) {
#pragma unroll
                    for (int k2 = 0; k2 < 4; ++k2) {
                        unsigned long long m = msk[k2];
                        while (m) {
                            const int j = (k2 << 6) + __builtin_ctzll(m);
                            m &= m - 1;
#pragma unroll
                            for (int k = 0; k < 4; ++k)
                                d3[k] += W3[(size_t)(l + 64 * k) * HID + j];
                        }
                    }
                }
#pragma unroll
                for (int k = 0; k < 4; ++k) acc[k] += d3[k];
            }
        }
#pragma unroll
        for (int k = 0; k < 4; ++k)
            hsh[l + 64 * k] = acc[k] * (1.0f / (float)BATCH);
    }
    __syncthreads();

    // ---- epilogue: relu(h@Wa1^T + ba1) @ Wa2^T + ba2 ----
    const float4 hv = ((const float4*)hsh)[l];
#pragma unroll 4
    for (int r = w; r < HID; r += 8) {
        const float4 wv = ((const float4*)(Wa1 + (size_t)r * HID))[l];
        const float a = wave_sum(wv.x * hv.x + wv.y * hv.y +
                                 wv.z * hv.z + wv.w * hv.w);
        if (l == 0) rsh[r] = fmaxf(a + ba1[r], 0.0f);
    }
    __syncthreads();

    if (w == 0) {
        float q = 0.f;
#pragma unroll
        for (int k = 0; k < 4; ++k)
            q += Wa2[l + 64 * k] * rsh[l + 64 * k];
        q = wave_sum(q);
        if (l == 0) out[b] = q + ba2[0];
    }
}

// ---------------------------------------------------------------------------
extern "C" void kernel_launch(void* const* d_in, const int* in_sizes, int n_in,
                              void* d_out, int out_size, void* d_ws, size_t ws_size,
                              hipStream_t stream)
{
    const int*   text   = (const int*)  d_in[0];
    // d_in[1] = text_lengths: unused by the reference
    const float* emb    = (const float*)d_in[2];
    const float* W1     = (const float*)d_in[3];
    const float* b1     = (const float*)d_in[4];
    const float* thr1   = (const float*)d_in[5];
    const float* leak1  = (const float*)d_in[6];
    const float* W2     = (const float*)d_in[7];
    const float* b2     = (const float*)d_in[8];
    const float* thr2   = (const float*)d_in[9];
    const float* leak2  = (const float*)d_in[10];
    const float* W3     = (const float*)d_in[11];
    const float* b3     = (const float*)d_in[12];
    const float* Wa1    = (const float*)d_in[13];
    const float* ba1    = (const float*)d_in[14];
    const float* Wa2    = (const float*)d_in[15];
    const float* ba2    = (const float*)d_in[16];
    float*       out    = (float*)d_out;

    (void)d_ws; (void)ws_size;   // single self-contained dispatch, no scratch

    snn_one_kernel<<<BATCH, 512, 0, stream>>>(
        text, emb, W1, b1, W2, b2, W3, b3,
        thr1, leak1, thr2, leak2,
        Wa1, ba1, Wa2, ba2, out);
}